// Round 7
// baseline (208.959 us; speedup 1.0000x reference)
//
#include <hip/hip_runtime.h>

#define E_ 16
#define DIN 256
#define DH 512
#define DOUT 256
#define BTOK 32768

typedef _Float16 half8 __attribute__((ext_vector_type(8)));
typedef _Float16 half4v __attribute__((ext_vector_type(4)));
typedef float float4v __attribute__((ext_vector_type(4)));

// ---------------- workspace layout (bytes) ----------------
#define OFF_P1      0u            // packed W1 fp16: 4 MB
#define OFF_P2      4194304u      // packed W2 fp16: 4 MB
#define OFF_XH      8388608u      // x fp16: 16 MB
#define OFF_SCR     25165824u     // per-assignment weighted out fp16: 32 MB
#define OFF_HIST    25165824u     // OVERLAY on scr: int[512*16] gate histograms (lifetime ends before mlp writes scr)
#define OFF_TIDX    58720256u     // int[B*2]
#define OFF_TW      58982400u     // float[B*2]
#define OFF_STOK    59244544u     // int[65536]: g = tok*2+slot per sorted assignment
#define OFF_SW      59506688u     // float[65536]
#define OFF_OFFS    59768960u     // int[17]
#define OFF_TMAP    59769216u     // int[2048] blockIdx -> (e<<16)|tile_in_e, -1 = idle
#define MLP_GRID    2048          // 8 XCD lanes x 256 slots (worst-case safe)

// ---------------- prep: fused pack (blocks 0..2047) + gate (blocks 2048..2559) ----------------
// pack: W1/W2 -> MFMA fragment layout fp16. frag (16x16x32): lane l holds
//       M[k=(l>>4)*8+j][n=l&15] per 32x16 tile.
// gate: fp32 gating + x->fp16; writes PER-BLOCK histogram (no global atomics, no zero-init).
__global__ __launch_bounds__(256) void prep_kernel(const float* __restrict__ W1,
                                                   const float* __restrict__ W2,
                                                   const float* __restrict__ x,
                                                   const float* __restrict__ Wg,
                                                   const float* __restrict__ bg,
                                                   _Float16* __restrict__ p1,
                                                   _Float16* __restrict__ p2,
                                                   _Float16* __restrict__ xh,
                                                   int* __restrict__ tidx,
                                                   float* __restrict__ tw,
                                                   int* __restrict__ hist) {
    __shared__ float WgS[DIN * E_];                   // 16 KB (gate branch only)
    __shared__ int hcnt[16];
    int tid = threadIdx.x;

    if (blockIdx.x < 2048) {
        // ---------------- pack branch ----------------
        int bid = blockIdx.x * 4 + (tid >> 6);
        int l = tid & 63;
        int quad = l >> 4, l15 = l & 15;
        if (bid < 4096) {          // W1: bid = (e*8 + kt)*32 + ht
            int ht = bid & 31, kt = (bid >> 5) & 7, e = bid >> 8;
            half8 v;
#pragma unroll
            for (int j = 0; j < 8; ++j)
                v[j] = (_Float16)W1[(e * DIN + kt * 32 + quad * 8 + j) * DH + ht * 16 + l15];
            ((half8*)p1)[bid * 64 + l] = v;
        } else {                   // W2: bid-4096 = (e*16 + kt2)*16 + ot
            int b2i = bid - 4096;
            int ot = b2i & 15, kt = (b2i >> 4) & 15, e = b2i >> 8;
            half8 v;
#pragma unroll
            for (int j = 0; j < 8; ++j)
                v[j] = (_Float16)W2[(e * DH + kt * 32 + quad * 8 + j) * DOUT + ot * 16 + l15];
            ((half8*)p2)[b2i * 64 + l] = v;
        }
        return;
    }

    // ---------------- gate branch ----------------
    int gb = blockIdx.x - 2048;                       // gate block 0..511 (64 tokens each)
    if (tid < 16) hcnt[tid] = 0;
#pragma unroll
    for (int i = 0; i < 4; ++i)
        ((float4v*)WgS)[tid + i * 256] = ((const float4v*)Wg)[tid + i * 256];
    __syncthreads();

    int q = tid & 7, tg = tid >> 3;                   // 32 groups x 2 tokens = 64 tokens/block
    int t0 = gb * 64 + tg * 2;

    float acc[2][16];
#pragma unroll
    for (int tt = 0; tt < 2; ++tt)
#pragma unroll
        for (int e = 0; e < 16; ++e) acc[tt][e] = 0.f;

#pragma unroll
    for (int ii = 0; ii < 8; ++ii) {                  // K-eighth: 32 floats = 8 float4
        int kb = q * 32 + ii * 4;
        float4v xv[2];
#pragma unroll
        for (int tt = 0; tt < 2; ++tt) {
            xv[tt] = *(const float4v*)&x[(t0 + tt) * DIN + kb];
            half4v hv;
#pragma unroll
            for (int j = 0; j < 4; ++j) hv[j] = (_Float16)xv[tt][j];
            *(half4v*)&xh[(t0 + tt) * DIN + kb] = hv;
        }
#pragma unroll
        for (int j = 0; j < 4; ++j) {
            const float4v* wrow = (const float4v*)&WgS[(kb + j) * 16];
            float4v w0 = wrow[0], w1 = wrow[1], w2 = wrow[2], w3 = wrow[3];
#pragma unroll
            for (int tt = 0; tt < 2; ++tt) {
                float xs = xv[tt][j];
#pragma unroll
                for (int c = 0; c < 4; ++c) {
                    acc[tt][0 + c]  += xs * w0[c];
                    acc[tt][4 + c]  += xs * w1[c];
                    acc[tt][8 + c]  += xs * w2[c];
                    acc[tt][12 + c] += xs * w3[c];
                }
            }
        }
    }
#pragma unroll
    for (int tt = 0; tt < 2; ++tt)
#pragma unroll
        for (int e = 0; e < 16; ++e) {
            acc[tt][e] += __shfl_xor(acc[tt][e], 1);
            acc[tt][e] += __shfl_xor(acc[tt][e], 2);
            acc[tt][e] += __shfl_xor(acc[tt][e], 4);
        }
    if (q == 0) {
#pragma unroll
        for (int tt = 0; tt < 2; ++tt) {
            int b = t0 + tt;
            float m1 = -3.4e38f, m2 = -3.4e38f;
            int i1 = 0, i2 = 0;
#pragma unroll
            for (int e = 0; e < 16; ++e) {
                float v = acc[tt][e] + bg[e];
                if (v > m1) { m2 = m1; i2 = i1; m1 = v; i1 = e; }
                else if (v > m2) { m2 = v; i2 = e; }
            }
            float e2 = __expf(m2 - m1);
            float w1 = 1.f / (1.f + e2);
            tidx[b * 2] = i1; tidx[b * 2 + 1] = i2;
            tw[b * 2] = w1;  tw[b * 2 + 1] = e2 * w1;
            atomicAdd(&hcnt[i1], 1);
            atomicAdd(&hcnt[i2], 1);
        }
    }
    __syncthreads();
    if (tid < 16) hist[gb * 16 + tid] = hcnt[tid];    // per-block histogram, no atomics
}

// ---------------- scatter (absorbs scan): deterministic placement from histograms ----------------
// block b handles assignments [b*256, b*256+256) = gate blocks {2b, 2b+1}.
// pos = offsets[e] + (# assignments to e in gate blocks < 2b) + rank-in-block.
// block 0 additionally publishes offsets[17] and the XCD-affine tmap.
__global__ __launch_bounds__(256) void scatter_kernel(const int* __restrict__ hist,
                                                      const int* __restrict__ tidx,
                                                      const float* __restrict__ tw,
                                                      int* __restrict__ offsets,
                                                      int* __restrict__ tmap,
                                                      int* __restrict__ stok,
                                                      float* __restrict__ sw) {
    __shared__ int part_tot[16][17];                  // [expert][chunk] (+1 pad col for reduce)
    __shared__ int part_pre[16][17];
    __shared__ int s_off[17];
    __shared__ int s_base[16];
    __shared__ int lc[16];
    int tid = threadIdx.x;
    int b = blockIdx.x;
    int e = tid & 15, ch = tid >> 4;                  // 16 experts x 16 chunks of 32 gate-blocks
    int gblim = b * 2;
    int t0 = 0, p0 = 0;
    for (int i = 0; i < 32; ++i) {
        int gb = ch * 32 + i;
        int v = hist[gb * 16 + e];
        t0 += v;
        if (gb < gblim) p0 += v;
    }
    part_tot[e][ch] = t0;
    part_pre[e][ch] = p0;
    if (tid < 16) lc[tid] = 0;
    __syncthreads();
    if (tid < 16) {
        int tot = 0, pre = 0;
#pragma unroll
        for (int c = 0; c < 16; ++c) { tot += part_tot[tid][c]; pre += part_pre[tid][c]; }
        part_tot[tid][16] = tot;
        part_pre[tid][16] = pre;
    }
    __syncthreads();
    if (tid == 0) {
        int run = 0;
#pragma unroll
        for (int e2 = 0; e2 < 16; ++e2) { s_off[e2] = run; run += part_tot[e2][16]; }
        s_off[16] = run;
    }
    __syncthreads();
    if (tid < 16) s_base[tid] = s_off[tid] + part_pre[tid][16];
    __syncthreads();

    int g = b * 256 + tid;
    int et = tidx[g];
    int rank = atomicAdd(&lc[et], 1);
    int pos = s_base[et] + rank;
    stok[pos] = g;                                    // g = tok*2 + slot
    sw[pos] = tw[g];

    if (b == 0) {
        if (tid < 17) offsets[tid] = s_off[tid];
        for (int i = tid; i < MLP_GRID; i += 256) tmap[i] = -1;
        __syncthreads();
        if (tid < 16) {
            int e2 = tid;
            int nt = (s_off[e2 + 1] - s_off[e2] + 63) >> 6;
            int xc = e2 & 7;
            int base = (e2 >= 8) ? ((s_off[e2 - 7] - s_off[e2 - 8] + 63) >> 6) : 0;
            for (int t = 0; t < nt; ++t) {
                int s = base + t;
                if (s < 256) tmap[xc + 8 * s] = (e2 << 16) | t;
            }
        }
    }
}

// ---------------- fused expert MLP (unchanged from v4) ----------------
// LDS: Xs 64x256 halfs (32 KB, swizzled) + Hs 64x256 halfs (32 KB, swizzled) = 64 KB
// v4: (a) one-kt-ahead register staging of weight fragments; (b) phase-2 operand swap:
//     mfma(bw, ha) computes (H*W2)^T with the SAME fragments -> lane-uniform routing
//     weight, vectorized epilogue.
#define XS 0
#define HS 16384
__global__ __launch_bounds__(512, 4) void mlp_kernel(const _Float16* __restrict__ xh,
                                                     const _Float16* __restrict__ p1,
                                                     const _Float16* __restrict__ p2,
                                                     const float* __restrict__ b1,
                                                     const float* __restrict__ b2,
                                                     const int* __restrict__ offsets,
                                                     const int* __restrict__ stok,
                                                     const float* __restrict__ sw,
                                                     const int* __restrict__ tmap,
                                                     _Float16* __restrict__ scr) {
    __shared__ _Float16 S[32768];                     // 64 KB
    const int tile = tmap[blockIdx.x];
    if (tile < 0) return;
    const int e = tile >> 16;
    const int ts = (tile & 0xffff) * 64;
    const int off = offsets[e];
    const int ne = offsets[e + 1] - off;
    const int rows = min(64, ne - ts);

    const int tid = threadIdx.x;
    const int w = tid >> 6;                           // wave 0..7
    const int l = tid & 63;
    const int l15 = l & 15;
    const int quad = l >> 4;

    // ---- stage X tile (64 tok x 256 halfs) into LDS, 16B-granule XOR swizzle ----
#pragma unroll
    for (int j = 0; j < 4; ++j) {
        int tokl = w * 8 + j * 2 + (l >> 5);          // local token row
        int slot = l & 31;                            // 16B slot within row
        int g = slot ^ (tokl & 7);                    // logical k-granule stored here
        int r = tokl; if (r >= rows) r = rows - 1;
        int tok = stok[off + ts + r] >> 1;
        half8 v = *(const half8*)&xh[tok * DIN + g * 8];
        *(half8*)&S[XS + tokl * 256 + slot * 8] = v;
    }

    const half8* p1b = (const half8*)p1;
    const half8* p2b = (const half8*)p2;

    float4v acc2[2][4];                               // [n][mt] (transposed result)
#pragma unroll
    for (int n = 0; n < 2; ++n)
#pragma unroll
        for (int mt = 0; mt < 4; ++mt) acc2[n][mt] = (float4v){0.f, 0.f, 0.f, 0.f};

    __syncthreads();

#pragma unroll
    for (int half = 0; half < 2; ++half) {
        // ---- phase 1: H[:, half*256 .. half*256+255] ; wave w owns h-tiles w*2, w*2+1 ----
        float4v acc1[2][4];
#pragma unroll
        for (int mh = 0; mh < 2; ++mh)
#pragma unroll
            for (int nt = 0; nt < 4; ++nt) acc1[mh][nt] = (float4v){0.f, 0.f, 0.f, 0.f};

        // weight staging: current + next kt fragments in flight
        half8 awc[2], awn[2];
#pragma unroll
        for (int mh = 0; mh < 2; ++mh)
            awc[mh] = p1b[((e * 8 + 0) * 32 + half * 16 + w * 2 + mh) * 64 + l];

#pragma unroll
        for (int kt = 0; kt < 8; ++kt) {
            int ktn = kt < 7 ? kt + 1 : 7;            // clamped prefetch (last = L1 re-hit)
#pragma unroll
            for (int mh = 0; mh < 2; ++mh)
                awn[mh] = p1b[((e * 8 + ktn) * 32 + half * 16 + w * 2 + mh) * 64 + l];
            half8 bq[4];
#pragma unroll
            for (int nt = 0; nt < 4; ++nt) {
                int row = nt * 16 + l15;
                int slot = (kt * 4 + quad) ^ (l15 & 7);
                bq[nt] = *(const half8*)&S[XS + row * 256 + slot * 8];
            }
#pragma unroll
            for (int mh = 0; mh < 2; ++mh) {
#pragma unroll
                for (int nt = 0; nt < 4; ++nt)
                    acc1[mh][nt] = __builtin_amdgcn_mfma_f32_16x16x32_f16(awc[mh], bq[nt], acc1[mh][nt], 0, 0, 0);
            }
            awc[0] = awn[0]; awc[1] = awn[1];
        }
        // bias + relu + store H-half (half4 per acc tile, swizzled)
#pragma unroll
        for (int mh = 0; mh < 2; ++mh) {
            int colh = (w * 2 + mh) * 16 + quad * 4;  // local h col (0..255)
            float4v b1q = *(const float4v*)&b1[e * DH + half * 256 + colh];
            int gq = colh >> 3;                       // 16B granule
            int go = (quad & 1) * 4;                  // half offset within granule
#pragma unroll
            for (int nt = 0; nt < 4; ++nt) {
                int row = nt * 16 + l15;
                int slot = gq ^ (l15 & 7);
                half4v hv;
#pragma unroll
                for (int r = 0; r < 4; ++r) {
                    float v = acc1[mh][nt][r] + b1q[r];
                    hv[r] = (_Float16)(v > 0.f ? v : 0.f);
                }
                *(half4v*)&S[HS + row * 256 + slot * 8 + go] = hv;
            }
        }
        __syncthreads();

        // ---- phase 2 partial (swapped operands): acc2^T += W2^T * H^T ----
        half8 bwc[2], bwn[2];
#pragma unroll
        for (int n = 0; n < 2; ++n)
            bwc[n] = p2b[((e * 16 + half * 8 + 0) * 16 + w * 2 + n) * 64 + l];

#pragma unroll
        for (int kt2 = 0; kt2 < 8; ++kt2) {
            int ktn = kt2 < 7 ? kt2 + 1 : 7;
#pragma unroll
            for (int n = 0; n < 2; ++n)
                bwn[n] = p2b[((e * 16 + half * 8 + ktn) * 16 + w * 2 + n) * 64 + l];
            half8 ha[4];
#pragma unroll
            for (int mt = 0; mt < 4; ++mt) {
                int row = mt * 16 + l15;
                int slot = (kt2 * 4 + quad) ^ (l15 & 7);
                ha[mt] = *(const half8*)&S[HS + row * 256 + slot * 8];
            }
#pragma unroll
            for (int n = 0; n < 2; ++n) {
#pragma unroll
                for (int mt = 0; mt < 4; ++mt)
                    acc2[n][mt] = __builtin_amdgcn_mfma_f32_16x16x32_f16(bwc[n], ha[mt], acc2[n][mt], 0, 0, 0);
            }
            bwc[0] = bwn[0]; bwc[1] = bwn[1];
        }
        __syncthreads();                              // H reads done before overwrite / reuse
    }

    // ---- epilogue: transposed acc -> lane holds 4 consecutive outcols of ONE token ----
    // acc2[n][mt] reg r = C[token = mt*16 + l15][outcol = (w*2+n)*16 + quad*4 + r]
#pragma unroll
    for (int n = 0; n < 2; ++n) {
        int col0 = (w * 2 + n) * 16 + quad * 4;       // first of 4 consecutive out cols
        float4v b2q = *(const float4v*)&b2[e * DOUT + col0];
        int gran = col0 >> 3;                         // 16B granule index
        int go = (quad & 1) * 4;                      // half offset within granule
#pragma unroll
        for (int mt = 0; mt < 4; ++mt) {
            int tok = mt * 16 + l15;                  // local token row
            int rc = tok < rows ? tok : rows - 1;
            float wt = sw[off + ts + rc];             // lane-uniform per (n,mt)
            half4v hv;
#pragma unroll
            for (int r = 0; r < 4; ++r)
                hv[r] = (_Float16)(wt * (acc2[n][mt][r] + b2q[r]));
            int slot = gran ^ (tok & 7);
            *(half4v*)&S[HS + tok * 256 + slot * 8 + go] = hv;
        }
    }
    __syncthreads();
#pragma unroll
    for (int p = 0; p < 4; ++p) {
        int idx = p * 512 + tid;
        int tok = idx >> 5;                           // local token row
        int sl = idx & 31;                            // logical 16B granule
        if (tok < rows) {
            int slot = sl ^ (tok & 7);
            half8 v = *(const half8*)&S[HS + tok * 256 + slot * 8];
            int g = stok[off + ts + tok];             // assignment slot = tok*2+sel
            *(half8*)&scr[g * DOUT + sl * 8] = v;
        }
    }
}

// ---------------- combine: out[t] = scr[t*2] + scr[t*2+1], streaming ----------------
__global__ __launch_bounds__(256) void combine_kernel(const _Float16* __restrict__ scr,
                                                      float* __restrict__ out) {
    int wv = threadIdx.x >> 6;
    int l = threadIdx.x & 63;
    int t = blockIdx.x * 4 + wv;
    half4v a = ((const half4v*)(scr + t * 2 * DOUT))[l];
    half4v b = ((const half4v*)(scr + t * 2 * DOUT + DOUT))[l];
    float4v o;
#pragma unroll
    for (int j = 0; j < 4; ++j) o[j] = (float)a[j] + (float)b[j];
    ((float4v*)(out + t * DOUT))[l] = o;
}

extern "C" void kernel_launch(void* const* d_in, const int* in_sizes, int n_in,
                              void* d_out, int out_size, void* d_ws, size_t ws_size,
                              hipStream_t stream) {
    const float* x  = (const float*)d_in[0];
    const float* Wg = (const float*)d_in[1];
    const float* bg = (const float*)d_in[2];
    const float* W1 = (const float*)d_in[3];
    const float* b1 = (const float*)d_in[4];
    const float* W2 = (const float*)d_in[5];
    const float* b2 = (const float*)d_in[6];
    float* out = (float*)d_out;

    char* ws = (char*)d_ws;
    _Float16* p1  = (_Float16*)(ws + OFF_P1);
    _Float16* p2  = (_Float16*)(ws + OFF_P2);
    _Float16* xh  = (_Float16*)(ws + OFF_XH);
    _Float16* scr = (_Float16*)(ws + OFF_SCR);
    int* hist     = (int*)(ws + OFF_HIST);            // overlays scr (disjoint lifetime)
    int* tidx     = (int*)(ws + OFF_TIDX);
    float* tw     = (float*)(ws + OFF_TW);
    int* stok     = (int*)(ws + OFF_STOK);
    float* swp    = (float*)(ws + OFF_SW);
    int* offsets  = (int*)(ws + OFF_OFFS);
    int* tmap     = (int*)(ws + OFF_TMAP);

    prep_kernel<<<dim3(2560), dim3(256), 0, stream>>>(W1, W2, x, Wg, bg, p1, p2, xh,
                                                      tidx, tw, hist);
    scatter_kernel<<<dim3(256), dim3(256), 0, stream>>>(hist, tidx, tw, offsets, tmap,
                                                        stok, swp);
    mlp_kernel<<<dim3(MLP_GRID), dim3(512), 0, stream>>>(xh, p1, p2, b1, b2, offsets,
                                                         stok, swp, tmap, scr);
    combine_kernel<<<dim3(8192), dim3(256), 0, stream>>>(scr, out);
}

// Round 8
// 190.682 us; speedup vs baseline: 1.0959x; 1.0959x over previous
//
#include <hip/hip_runtime.h>

#define E_ 16
#define DIN 256
#define DH 512
#define DOUT 256
#define BTOK 32768

typedef _Float16 half8 __attribute__((ext_vector_type(8)));
typedef _Float16 half4v __attribute__((ext_vector_type(4)));
typedef float float4v __attribute__((ext_vector_type(4)));

// ---------------- workspace layout (bytes) ----------------
#define OFF_P1      0u            // packed W1 fp16: 4 MB
#define OFF_P2      4194304u      // packed W2 fp16: 4 MB
#define OFF_XH      8388608u      // x fp16: 16 MB
#define OFF_SCR     25165824u     // per-assignment weighted out fp16: 32 MB
#define OFF_HIST    25165824u     // OVERLAY on scr: int[512*16] gate histograms (lifetime ends before mlp writes scr)
#define OFF_TIDX    58720256u     // int[B*2]
#define OFF_TW      58982400u     // float[B*2]
#define OFF_STOK    59244544u     // int[65536]: g = tok*2+slot per sorted assignment
#define OFF_SW      59506688u     // float[65536]
#define OFF_OFFS    59768960u     // int[17]
#define OFF_TMAP    59769216u     // int[2048] blockIdx -> (e<<16)|tile_in_e, -1 = idle
#define MLP_GRID    2048          // 8 XCD lanes x 256 slots (worst-case safe)

// ---------------- prep: fused pack (blocks 0..255, LDS-transpose) + gate (blocks 256..767) ----
// pack v2: coalesced float4 global reads -> fp16 -> LDS stored TRANSPOSED [col][40],
//          fragment gather becomes one 16B LDS read per half8; global frag store coalesced.
// gate: fp32 gating + x->fp16; per-block histogram (no global atomics, no zero-init).
__global__ __launch_bounds__(256) void prep_kernel(const float* __restrict__ W1,
                                                   const float* __restrict__ W2,
                                                   const float* __restrict__ x,
                                                   const float* __restrict__ Wg,
                                                   const float* __restrict__ bg,
                                                   _Float16* __restrict__ p1,
                                                   _Float16* __restrict__ p2,
                                                   _Float16* __restrict__ xh,
                                                   int* __restrict__ tidx,
                                                   float* __restrict__ tw,
                                                   int* __restrict__ hist) {
    __shared__ __align__(16) _Float16 SP[20480];      // 40 KB pool (pack slab / gate WgS)
    __shared__ int hcnt[16];
    int tid = threadIdx.x;

    if (blockIdx.x < 256) {
        // ---------------- pack branch ----------------
        int l = tid & 63;
        int w4 = tid >> 6;                            // wave 0..3
        int quad = l >> 4, l15 = l & 15;
        if (blockIdx.x < 128) {
            // W1 slab: 32 rows (k) x 512 cols (h); e = b>>3, kt = b&7
            int e = blockIdx.x >> 3, kt = blockIdx.x & 7;
            const float* src = W1 + (e * DIN + kt * 32) * DH;
#pragma unroll
            for (int i = 0; i < 16; ++i) {            // 2 rows per iteration
                int r = i * 2 + (tid >> 7);
                int c0 = (tid & 127) * 4;
                float4v f = *(const float4v*)&src[r * DH + c0];
#pragma unroll
                for (int k = 0; k < 4; ++k)
                    SP[(c0 + k) * 40 + r] = (_Float16)f[k];   // transposed store
            }
            __syncthreads();
            half8* dst = (half8*)p1 + (e * 8 + kt) * 32 * 64;
#pragma unroll
            for (int hh = 0; hh < 8; ++hh) {
                int ht = w4 * 8 + hh;
                half8 v = *(const half8*)&SP[(ht * 16 + l15) * 40 + quad * 8];
                dst[ht * 64 + l] = v;                 // coalesced 16B/lane
            }
        } else {
            // W2 double-slab: 2 x (32 rows (k) x 256 cols (o)); e = bb>>3, pair = bb&7
            int bb = blockIdx.x - 128;
            int e = bb >> 3, pair = bb & 7;
            const float* src = W2 + (e * DH + pair * 64) * DOUT;
#pragma unroll
            for (int i = 0; i < 16; ++i) {            // s = sub-slab, 4 rows per iteration
                int s = i >> 3;
                int r = (i & 7) * 4 + (tid >> 6);
                int c0 = (tid & 63) * 4;
                float4v f = *(const float4v*)&src[(s * 32 + r) * DOUT + c0];
#pragma unroll
                for (int k = 0; k < 4; ++k)
                    SP[s * 10240 + (c0 + k) * 40 + r] = (_Float16)f[k];
            }
            __syncthreads();
#pragma unroll
            for (int ss = 0; ss < 2; ++ss) {
                int kt2 = pair * 2 + ss;
                half8* dst = (half8*)p2 + (e * 16 + kt2) * 16 * 64;
#pragma unroll
                for (int oo = 0; oo < 4; ++oo) {
                    int ot = w4 * 4 + oo;
                    half8 v = *(const half8*)&SP[ss * 10240 + (ot * 16 + l15) * 40 + quad * 8];
                    dst[ot * 64 + l] = v;
                }
            }
        }
        return;
    }

    // ---------------- gate branch ----------------
    float* WgS = (float*)SP;                          // 16 KB of the pool
    int gb = blockIdx.x - 256;                        // gate block 0..511 (64 tokens each)
    if (tid < 16) hcnt[tid] = 0;
#pragma unroll
    for (int i = 0; i < 4; ++i)
        ((float4v*)WgS)[tid + i * 256] = ((const float4v*)Wg)[tid + i * 256];
    __syncthreads();

    int q = tid & 7, tg = tid >> 3;                   // 32 groups x 2 tokens = 64 tokens/block
    int t0 = gb * 64 + tg * 2;

    float acc[2][16];
#pragma unroll
    for (int tt = 0; tt < 2; ++tt)
#pragma unroll
        for (int e = 0; e < 16; ++e) acc[tt][e] = 0.f;

#pragma unroll
    for (int ii = 0; ii < 8; ++ii) {                  // K-eighth: 32 floats = 8 float4
        int kb = q * 32 + ii * 4;
        float4v xv[2];
#pragma unroll
        for (int tt = 0; tt < 2; ++tt) {
            xv[tt] = *(const float4v*)&x[(t0 + tt) * DIN + kb];
            half4v hv;
#pragma unroll
            for (int j = 0; j < 4; ++j) hv[j] = (_Float16)xv[tt][j];
            *(half4v*)&xh[(t0 + tt) * DIN + kb] = hv;
        }
#pragma unroll
        for (int j = 0; j < 4; ++j) {
            const float4v* wrow = (const float4v*)&WgS[(kb + j) * 16];
            float4v w0 = wrow[0], w1 = wrow[1], w2 = wrow[2], w3 = wrow[3];
#pragma unroll
            for (int tt = 0; tt < 2; ++tt) {
                float xs = xv[tt][j];
#pragma unroll
                for (int c = 0; c < 4; ++c) {
                    acc[tt][0 + c]  += xs * w0[c];
                    acc[tt][4 + c]  += xs * w1[c];
                    acc[tt][8 + c]  += xs * w2[c];
                    acc[tt][12 + c] += xs * w3[c];
                }
            }
        }
    }
#pragma unroll
    for (int tt = 0; tt < 2; ++tt)
#pragma unroll
        for (int e = 0; e < 16; ++e) {
            acc[tt][e] += __shfl_xor(acc[tt][e], 1);
            acc[tt][e] += __shfl_xor(acc[tt][e], 2);
            acc[tt][e] += __shfl_xor(acc[tt][e], 4);
        }
    if (q == 0) {
#pragma unroll
        for (int tt = 0; tt < 2; ++tt) {
            int b = t0 + tt;
            float m1 = -3.4e38f, m2 = -3.4e38f;
            int i1 = 0, i2 = 0;
#pragma unroll
            for (int e = 0; e < 16; ++e) {
                float v = acc[tt][e] + bg[e];
                if (v > m1) { m2 = m1; i2 = i1; m1 = v; i1 = e; }
                else if (v > m2) { m2 = v; i2 = e; }
            }
            float e2 = __expf(m2 - m1);
            float w1 = 1.f / (1.f + e2);
            tidx[b * 2] = i1; tidx[b * 2 + 1] = i2;
            tw[b * 2] = w1;  tw[b * 2 + 1] = e2 * w1;
            atomicAdd(&hcnt[i1], 1);
            atomicAdd(&hcnt[i2], 1);
        }
    }
    __syncthreads();
    if (tid < 16) hist[gb * 16 + tid] = hcnt[tid];    // per-block histogram, no atomics
}

// ---------------- scatter (absorbs scan): deterministic placement from histograms ----------------
__global__ __launch_bounds__(256) void scatter_kernel(const int* __restrict__ hist,
                                                      const int* __restrict__ tidx,
                                                      const float* __restrict__ tw,
                                                      int* __restrict__ offsets,
                                                      int* __restrict__ tmap,
                                                      int* __restrict__ stok,
                                                      float* __restrict__ sw) {
    __shared__ int part_tot[16][17];                  // [expert][chunk] (+1 pad col)
    __shared__ int part_pre[16][17];
    __shared__ int s_off[17];
    __shared__ int s_base[16];
    __shared__ int lc[16];
    int tid = threadIdx.x;
    int b = blockIdx.x;
    int e = tid & 15, ch = tid >> 4;                  // 16 experts x 16 chunks of 32 gate-blocks
    int gblim = b * 2;
    int t0 = 0, p0 = 0;
    for (int i = 0; i < 32; ++i) {
        int gb = ch * 32 + i;
        int v = hist[gb * 16 + e];
        t0 += v;
        if (gb < gblim) p0 += v;
    }
    part_tot[e][ch] = t0;
    part_pre[e][ch] = p0;
    if (tid < 16) lc[tid] = 0;
    __syncthreads();
    if (tid < 16) {
        int tot = 0, pre = 0;
#pragma unroll
        for (int c = 0; c < 16; ++c) { tot += part_tot[tid][c]; pre += part_pre[tid][c]; }
        part_tot[tid][16] = tot;
        part_pre[tid][16] = pre;
    }
    __syncthreads();
    if (tid == 0) {
        int run = 0;
#pragma unroll
        for (int e2 = 0; e2 < 16; ++e2) { s_off[e2] = run; run += part_tot[e2][16]; }
        s_off[16] = run;
    }
    __syncthreads();
    if (tid < 16) s_base[tid] = s_off[tid] + part_pre[tid][16];
    __syncthreads();

    int g = b * 256 + tid;
    int et = tidx[g];
    int rank = atomicAdd(&lc[et], 1);
    int pos = s_base[et] + rank;
    stok[pos] = g;                                    // g = tok*2 + slot
    sw[pos] = tw[g];

    if (b == 0) {
        if (tid < 17) offsets[tid] = s_off[tid];
        for (int i = tid; i < MLP_GRID; i += 256) tmap[i] = -1;
        __syncthreads();
        if (tid < 16) {
            int e2 = tid;
            int nt = (s_off[e2 + 1] - s_off[e2] + 63) >> 6;
            int xc = e2 & 7;
            int base = (e2 >= 8) ? ((s_off[e2 - 7] - s_off[e2 - 8] + 63) >> 6) : 0;
            for (int t = 0; t < nt; ++t) {
                int s = base + t;
                if (s < 256) tmap[xc + 8 * s] = (e2 << 16) | t;
            }
        }
    }
}

// ---------------- fused expert MLP (unchanged from v4) ----------------
#define XS 0
#define HS 16384
__global__ __launch_bounds__(512, 4) void mlp_kernel(const _Float16* __restrict__ xh,
                                                     const _Float16* __restrict__ p1,
                                                     const _Float16* __restrict__ p2,
                                                     const float* __restrict__ b1,
                                                     const float* __restrict__ b2,
                                                     const int* __restrict__ offsets,
                                                     const int* __restrict__ stok,
                                                     const float* __restrict__ sw,
                                                     const int* __restrict__ tmap,
                                                     _Float16* __restrict__ scr) {
    __shared__ _Float16 S[32768];                     // 64 KB
    const int tile = tmap[blockIdx.x];
    if (tile < 0) return;
    const int e = tile >> 16;
    const int ts = (tile & 0xffff) * 64;
    const int off = offsets[e];
    const int ne = offsets[e + 1] - off;
    const int rows = min(64, ne - ts);

    const int tid = threadIdx.x;
    const int w = tid >> 6;                           // wave 0..7
    const int l = tid & 63;
    const int l15 = l & 15;
    const int quad = l >> 4;

    // ---- stage X tile (64 tok x 256 halfs) into LDS, 16B-granule XOR swizzle ----
#pragma unroll
    for (int j = 0; j < 4; ++j) {
        int tokl = w * 8 + j * 2 + (l >> 5);          // local token row
        int slot = l & 31;                            // 16B slot within row
        int g = slot ^ (tokl & 7);                    // logical k-granule stored here
        int r = tokl; if (r >= rows) r = rows - 1;
        int tok = stok[off + ts + r] >> 1;
        half8 v = *(const half8*)&xh[tok * DIN + g * 8];
        *(half8*)&S[XS + tokl * 256 + slot * 8] = v;
    }

    const half8* p1b = (const half8*)p1;
    const half8* p2b = (const half8*)p2;

    float4v acc2[2][4];                               // [n][mt] (transposed result)
#pragma unroll
    for (int n = 0; n < 2; ++n)
#pragma unroll
        for (int mt = 0; mt < 4; ++mt) acc2[n][mt] = (float4v){0.f, 0.f, 0.f, 0.f};

    __syncthreads();

#pragma unroll
    for (int half = 0; half < 2; ++half) {
        // ---- phase 1: H[:, half*256 .. half*256+255] ; wave w owns h-tiles w*2, w*2+1 ----
        float4v acc1[2][4];
#pragma unroll
        for (int mh = 0; mh < 2; ++mh)
#pragma unroll
            for (int nt = 0; nt < 4; ++nt) acc1[mh][nt] = (float4v){0.f, 0.f, 0.f, 0.f};

        // weight staging: current + next kt fragments in flight
        half8 awc[2], awn[2];
#pragma unroll
        for (int mh = 0; mh < 2; ++mh)
            awc[mh] = p1b[((e * 8 + 0) * 32 + half * 16 + w * 2 + mh) * 64 + l];

#pragma unroll
        for (int kt = 0; kt < 8; ++kt) {
            int ktn = kt < 7 ? kt + 1 : 7;            // clamped prefetch (last = L1 re-hit)
#pragma unroll
            for (int mh = 0; mh < 2; ++mh)
                awn[mh] = p1b[((e * 8 + ktn) * 32 + half * 16 + w * 2 + mh) * 64 + l];
            half8 bq[4];
#pragma unroll
            for (int nt = 0; nt < 4; ++nt) {
                int row = nt * 16 + l15;
                int slot = (kt * 4 + quad) ^ (l15 & 7);
                bq[nt] = *(const half8*)&S[XS + row * 256 + slot * 8];
            }
#pragma unroll
            for (int mh = 0; mh < 2; ++mh) {
#pragma unroll
                for (int nt = 0; nt < 4; ++nt)
                    acc1[mh][nt] = __builtin_amdgcn_mfma_f32_16x16x32_f16(awc[mh], bq[nt], acc1[mh][nt], 0, 0, 0);
            }
            awc[0] = awn[0]; awc[1] = awn[1];
        }
        // bias + relu + store H-half (half4 per acc tile, swizzled)
#pragma unroll
        for (int mh = 0; mh < 2; ++mh) {
            int colh = (w * 2 + mh) * 16 + quad * 4;  // local h col (0..255)
            float4v b1q = *(const float4v*)&b1[e * DH + half * 256 + colh];
            int gq = colh >> 3;                       // 16B granule
            int go = (quad & 1) * 4;                  // half offset within granule
#pragma unroll
            for (int nt = 0; nt < 4; ++nt) {
                int row = nt * 16 + l15;
                int slot = gq ^ (l15 & 7);
                half4v hv;
#pragma unroll
                for (int r = 0; r < 4; ++r) {
                    float v = acc1[mh][nt][r] + b1q[r];
                    hv[r] = (_Float16)(v > 0.f ? v : 0.f);
                }
                *(half4v*)&S[HS + row * 256 + slot * 8 + go] = hv;
            }
        }
        __syncthreads();

        // ---- phase 2 partial (swapped operands): acc2^T += W2^T * H^T ----
        half8 bwc[2], bwn[2];
#pragma unroll
        for (int n = 0; n < 2; ++n)
            bwc[n] = p2b[((e * 16 + half * 8 + 0) * 16 + w * 2 + n) * 64 + l];

#pragma unroll
        for (int kt2 = 0; kt2 < 8; ++kt2) {
            int ktn = kt2 < 7 ? kt2 + 1 : 7;
#pragma unroll
            for (int n = 0; n < 2; ++n)
                bwn[n] = p2b[((e * 16 + half * 8 + ktn) * 16 + w * 2 + n) * 64 + l];
            half8 ha[4];
#pragma unroll
            for (int mt = 0; mt < 4; ++mt) {
                int row = mt * 16 + l15;
                int slot = (kt2 * 4 + quad) ^ (l15 & 7);
                ha[mt] = *(const half8*)&S[HS + row * 256 + slot * 8];
            }
#pragma unroll
            for (int n = 0; n < 2; ++n) {
#pragma unroll
                for (int mt = 0; mt < 4; ++mt)
                    acc2[n][mt] = __builtin_amdgcn_mfma_f32_16x16x32_f16(bwc[n], ha[mt], acc2[n][mt], 0, 0, 0);
            }
            bwc[0] = bwn[0]; bwc[1] = bwn[1];
        }
        __syncthreads();                              // H reads done before overwrite / reuse
    }

    // ---- epilogue: transposed acc -> lane holds 4 consecutive outcols of ONE token ----
#pragma unroll
    for (int n = 0; n < 2; ++n) {
        int col0 = (w * 2 + n) * 16 + quad * 4;       // first of 4 consecutive out cols
        float4v b2q = *(const float4v*)&b2[e * DOUT + col0];
        int gran = col0 >> 3;                         // 16B granule index
        int go = (quad & 1) * 4;                      // half offset within granule
#pragma unroll
        for (int mt = 0; mt < 4; ++mt) {
            int tok = mt * 16 + l15;                  // local token row
            int rc = tok < rows ? tok : rows - 1;
            float wt = sw[off + ts + rc];             // lane-uniform per (n,mt)
            half4v hv;
#pragma unroll
            for (int r = 0; r < 4; ++r)
                hv[r] = (_Float16)(wt * (acc2[n][mt][r] + b2q[r]));
            int slot = gran ^ (tok & 7);
            *(half4v*)&S[HS + tok * 256 + slot * 8 + go] = hv;
        }
    }
    __syncthreads();
#pragma unroll
    for (int p = 0; p < 4; ++p) {
        int idx = p * 512 + tid;
        int tok = idx >> 5;                           // local token row
        int sl = idx & 31;                            // logical 16B granule
        if (tok < rows) {
            int slot = sl ^ (tok & 7);
            half8 v = *(const half8*)&S[HS + tok * 256 + slot * 8];
            int g = stok[off + ts + tok];             // assignment slot = tok*2+sel
            *(half8*)&scr[g * DOUT + sl * 8] = v;
        }
    }
}

// ---------------- combine: out[t] = scr[t*2] + scr[t*2+1], streaming ----------------
__global__ __launch_bounds__(256) void combine_kernel(const _Float16* __restrict__ scr,
                                                      float* __restrict__ out) {
    int wv = threadIdx.x >> 6;
    int l = threadIdx.x & 63;
    int t = blockIdx.x * 4 + wv;
    half4v a = ((const half4v*)(scr + t * 2 * DOUT))[l];
    half4v b = ((const half4v*)(scr + t * 2 * DOUT + DOUT))[l];
    float4v o;
#pragma unroll
    for (int j = 0; j < 4; ++j) o[j] = (float)a[j] + (float)b[j];
    ((float4v*)(out + t * DOUT))[l] = o;
}

extern "C" void kernel_launch(void* const* d_in, const int* in_sizes, int n_in,
                              void* d_out, int out_size, void* d_ws, size_t ws_size,
                              hipStream_t stream) {
    const float* x  = (const float*)d_in[0];
    const float* Wg = (const float*)d_in[1];
    const float* bg = (const float*)d_in[2];
    const float* W1 = (const float*)d_in[3];
    const float* b1 = (const float*)d_in[4];
    const float* W2 = (const float*)d_in[5];
    const float* b2 = (const float*)d_in[6];
    float* out = (float*)d_out;

    char* ws = (char*)d_ws;
    _Float16* p1  = (_Float16*)(ws + OFF_P1);
    _Float16* p2  = (_Float16*)(ws + OFF_P2);
    _Float16* xh  = (_Float16*)(ws + OFF_XH);
    _Float16* scr = (_Float16*)(ws + OFF_SCR);
    int* hist     = (int*)(ws + OFF_HIST);            // overlays scr (disjoint lifetime)
    int* tidx     = (int*)(ws + OFF_TIDX);
    float* tw     = (float*)(ws + OFF_TW);
    int* stok     = (int*)(ws + OFF_STOK);
    float* swp    = (float*)(ws + OFF_SW);
    int* offsets  = (int*)(ws + OFF_OFFS);
    int* tmap     = (int*)(ws + OFF_TMAP);

    prep_kernel<<<dim3(768), dim3(256), 0, stream>>>(W1, W2, x, Wg, bg, p1, p2, xh,
                                                     tidx, tw, hist);
    scatter_kernel<<<dim3(256), dim3(256), 0, stream>>>(hist, tidx, tw, offsets, tmap,
                                                        stok, swp);
    mlp_kernel<<<dim3(MLP_GRID), dim3(512), 0, stream>>>(xh, p1, p2, b1, b2, offsets,
                                                         stok, swp, tmap, scr);
    combine_kernel<<<dim3(8192), dim3(256), 0, stream>>>(scr, out);
}